// Round 13
// baseline (241.848 us; speedup 1.0000x reference)
//
#include <hip/hip_runtime.h>
#include <float.h>

// VQ-VAE nearest-codeword + loss, bf16x2-emulated fp32 GEMM on MFMA.
// feature: [8192, 512] fp32 -> rows f: [32768, 128]
// W: [2048, 128] fp32
// d_out: loss[8192] fp32, then out[32768*128] fp32
// R13: single fused kernel. W is converted fp32->bf16 hi/lo + wsq IN-KERNEL,
// staged per 128-code chunk into LDS (shared by all waves), XOR-swizzled frag
// slots for conflict-free ds_write/ds_read. No prep kernel, no d_ws use.
// Diagnosis from R12: per-wave global W streaming = 2 GB cache traffic; spills
// already fixed (WRITE 16.4MB). This moves W reuse into LDS (512 MB traffic).

#define NROWS 32768
#define DIM   128
#define NCODE 2048
#define BM    64             // rows per block -> grid 512 = 2 blocks/CU
#define NCB   16             // code chunks (128 codes each)
#define TAU   0.02f          // rescore threshold (bf16x2 3-pass error ~2e-3)

typedef __attribute__((ext_vector_type(8))) short short8v;  // 8 bf16 (4 VGPR)
typedef __attribute__((ext_vector_type(4))) float f32x4;

static __device__ __forceinline__ unsigned short f2bf_rne(float x) {
    unsigned u = __float_as_uint(x);
    unsigned r = u + 0x7FFFu + ((u >> 16) & 1u);
    return (unsigned short)(r >> 16);
}
static __device__ __forceinline__ float bf2f(unsigned short h) {
    return __uint_as_float(((unsigned)h) << 16);
}

// 256 threads = 4 waves, each wave owns 16 rows (rf=1) x all 2048 codes.
// Per chunk: all threads cooperatively convert+stage 128 codes of W into LDS
// (hi/lo bf16, frag-major, swizzled), then every wave computes 8 tiles.
__global__ __launch_bounds__(256, 2)
void vq_fused(const float* __restrict__ feature, const float* __restrict__ W,
              float* __restrict__ out) {
    __shared__ short lds_bh[16384];    // 32 KB: chunk hi  [tile][kc][gg][slot][8]
    __shared__ short lds_bl[16384];    // 32 KB: chunk lo
    __shared__ float wsq_l[NCODE];     // 8 KB (filled progressively per chunk)
    __shared__ float dist_l[BM];
    __shared__ int   j_l[BM];
    __shared__ float fsq_l[BM];
    __shared__ int   flags[BM + 4];
    __shared__ float frow[DIM];
    __shared__ float rbest[4];
    __shared__ int   rbj[4];

    const int tid  = threadIdx.x;
    const int lane = tid & 63;
    const int w    = tid >> 6;     // wave 0..3 -> rows w*16..w*16+15
    const int c    = lane & 15;
    const int g    = lane >> 4;    // 0..3
    const int rb   = blockIdx.x;   // 512 blocks of 64 rows

    if (tid == 0) flags[0] = 0;

    // ---- A-fragments (rf=1): lane holds f[row=c][k=kc*32+g*8+e], bf16 hi/lo ----
    short8v Ahi[4], Alo[4];
    {
        const int row = rb * BM + w * 16 + c;
        const float* fp = feature + (size_t)row * DIM + g * 8;
        float fs = 0.0f;
        #pragma unroll
        for (int kc = 0; kc < 4; ++kc) {
            float4 u0 = *(const float4*)(fp + kc * 32);
            float4 u1 = *(const float4*)(fp + kc * 32 + 4);
            float xs[8] = { u0.x, u0.y, u0.z, u0.w, u1.x, u1.y, u1.z, u1.w };
            short8v hi, lo;
            #pragma unroll
            for (int e = 0; e < 8; ++e) {
                unsigned short hb = f2bf_rne(xs[e]);
                float rem = xs[e] - bf2f(hb);
                unsigned short lb = f2bf_rne(rem);
                hi[e] = (short)hb; lo[e] = (short)lb;
                fs = fmaf(xs[e], xs[e], fs);
            }
            Ahi[kc] = hi; Alo[kc] = lo;
        }
        fs += __shfl_xor(fs, 16, 64);
        fs += __shfl_xor(fs, 32, 64);
        if (g == 0) fsq_l[w * 16 + c] = fs;
    }

    float s1[4], s2[4];
    int   j1[4];
    #pragma unroll
    for (int q = 0; q < 4; ++q) { s1[q] = FLT_MAX; s2[q] = FLT_MAX; j1[q] = NCODE; }

    #define VQ_COMPUTE(CODEBASE, Bh, Bl) do {                                      \
        const float wq = wsq_l[(CODEBASE)];                                        \
        f32x4 ahh = {0.f, 0.f, 0.f, 0.f};                                          \
        f32x4 ahl = {0.f, 0.f, 0.f, 0.f};                                          \
        f32x4 alh = {0.f, 0.f, 0.f, 0.f};                                          \
        _Pragma("unroll")                                                          \
        for (int kc = 0; kc < 4; ++kc) {                                           \
            ahh = __builtin_amdgcn_mfma_f32_16x16x32_bf16(Ahi[kc], Bh[kc], ahh, 0, 0, 0); \
            ahl = __builtin_amdgcn_mfma_f32_16x16x32_bf16(Ahi[kc], Bl[kc], ahl, 0, 0, 0); \
            alh = __builtin_amdgcn_mfma_f32_16x16x32_bf16(Alo[kc], Bh[kc], alh, 0, 0, 0); \
        }                                                                          \
        _Pragma("unroll")                                                          \
        for (int q = 0; q < 4; ++q) {                                              \
            float dot = ahh[q] + ahl[q] + alh[q];                                  \
            float s   = fmaf(-2.0f, dot, wq);                                      \
            bool  lt  = s < s1[q];                                                 \
            s2[q] = fminf(s2[q], lt ? s1[q] : s);                                  \
            j1[q] = lt ? (CODEBASE) : j1[q];                                       \
            s1[q] = lt ? s : s1[q];                                                \
        }                                                                          \
    } while (0)

    for (int cb = 0; cb < NCB; ++cb) {
        __syncthreads();   // prior compute done; LDS chunk buffer reusable

        // ---- stage chunk cb: convert 128 codes of W -> hi/lo frags + wsq ----
        // thread handles 8 (code,g) pairs; lanes sharing a code are the 16
        // low-lane group -> shfl-reduce wsq. Frag slot XOR-swizzled on c:
        // slot = (c2 ^ gdim) & 15 (same formula on read) -> conflict-free.
        #pragma unroll
        for (int i = 0; i < 8; ++i) {
            const int p    = tid + i * 256;   // 0..2047
            const int cc   = p >> 4;          // code in chunk 0..127
            const int gdim = p & 15;          // dim group 0..15
            const float* src = W + ((size_t)(cb * 128 + cc)) * DIM + gdim * 8;
            float4 u0 = *(const float4*)(src);
            float4 u1 = *(const float4*)(src + 4);
            float xs[8] = { u0.x, u0.y, u0.z, u0.w, u1.x, u1.y, u1.z, u1.w };
            short8v hi, lo;
            float ps = 0.0f;
            #pragma unroll
            for (int e = 0; e < 8; ++e) {
                unsigned short hb = f2bf_rne(xs[e]);
                float rem = xs[e] - bf2f(hb);
                unsigned short lb = f2bf_rne(rem);
                hi[e] = (short)hb; lo[e] = (short)lb;
                ps = fmaf(xs[e], xs[e], ps);
            }
            const int tile = cc >> 4;
            const int c2   = cc & 15;
            const int kc   = gdim >> 2;
            const int gg   = gdim & 3;
            const int off  = tile * 2048 + kc * 512 + gg * 128 + ((c2 ^ gdim) & 15) * 8;
            *(short8v*)&lds_bh[off] = hi;
            *(short8v*)&lds_bl[off] = lo;
            ps += __shfl_xor(ps, 1, 64);
            ps += __shfl_xor(ps, 2, 64);
            ps += __shfl_xor(ps, 4, 64);
            ps += __shfl_xor(ps, 8, 64);
            if (gdim == 0) wsq_l[cb * 128 + cc] = ps;
        }
        __syncthreads();   // chunk + wsq ready

        // ---- compute: 8 tiles of 16 codes ----
        #pragma unroll
        for (int t = 0; t < 8; ++t) {
            short8v Bh[4], Bl[4];
            #pragma unroll
            for (int kc = 0; kc < 4; ++kc) {
                const int off = t * 2048 + kc * 512 + g * 128 + ((c ^ (kc * 4 + g)) & 15) * 8;
                Bh[kc] = *(const short8v*)&lds_bh[off];
                Bl[kc] = *(const short8v*)&lds_bl[off];
            }
            VQ_COMPUTE(cb * 128 + t * 16 + c, Bh, Bl);
        }
    }
    #undef VQ_COMPUTE

    // ---- cross-lane top-2 merge over the 16 code-lanes ----
    #pragma unroll
    for (int q = 0; q < 4; ++q) {
        float a1 = s1[q]; int aj = j1[q]; float a2 = s2[q];
        #pragma unroll
        for (int m = 1; m < 16; m <<= 1) {
            float b1 = __shfl_xor(a1, m, 64);
            int   bj = __shfl_xor(aj, m, 64);
            float b2 = __shfl_xor(a2, m, 64);
            bool swap = (b1 < a1) || (b1 == a1 && bj < aj);
            float other1 = swap ? a1 : b1;
            a2 = fminf(fminf(a2, b2), other1);
            a1 = swap ? b1 : a1;
            aj = swap ? bj : aj;
        }
        if (c == 0) {
            const int row = w * 16 + g * 4 + q;
            dist_l[row] = a1;
            j_l[row]    = aj;
            if (a2 - a1 < TAU) {
                int idx = atomicAdd(&flags[0], 1);
                flags[1 + idx] = row;
            }
        }
    }
    __syncthreads();

    // ---- exact fp32 rescore for flagged rows (rare) ----
    const int nf = flags[0];
    for (int i = 0; i < nf; ++i) {
        const int row = flags[1 + i];
        if (tid < 32) {
            float4 v = *(const float4*)(feature + ((size_t)(rb * BM + row)) * DIM + tid * 4);
            *(float4*)&frow[tid * 4] = v;
        }
        __syncthreads();
        float best = FLT_MAX; int bj = NCODE;
        #pragma unroll 1
        for (int cc = 0; cc < 8; ++cc) {
            const int code = tid * 8 + cc;
            const float* wp = W + (size_t)code * DIM;
            float d = 0.0f;
            #pragma unroll
            for (int k = 0; k < DIM; k += 4) {
                float4 wv = *(const float4*)(wp + k);
                d = fmaf(wv.x, frow[k],     d);
                d = fmaf(wv.y, frow[k + 1], d);
                d = fmaf(wv.z, frow[k + 2], d);
                d = fmaf(wv.w, frow[k + 3], d);
            }
            float s = wsq_l[code] - 2.0f * d;
            if (s < best) { best = s; bj = code; }
        }
        #pragma unroll
        for (int m = 1; m < 64; m <<= 1) {
            float ob = __shfl_xor(best, m, 64);
            int   oj = __shfl_xor(bj, m, 64);
            if (ob < best || (ob == best && oj < bj)) { best = ob; bj = oj; }
        }
        if (lane == 0) { rbest[w] = best; rbj[w] = bj; }
        __syncthreads();
        if (tid == 0) {
            float bb = rbest[0]; int jj = rbj[0];
            #pragma unroll
            for (int ww = 1; ww < 4; ++ww) {
                if (rbest[ww] < bb || (rbest[ww] == bb && rbj[ww] < jj)) { bb = rbest[ww]; jj = rbj[ww]; }
            }
            dist_l[row] = bb; j_l[row] = jj;
        }
        __syncthreads();
    }

    // ---- loss: 16 batch rows per block ----
    if (tid < 16) {
        float s = 0.0f;
        #pragma unroll
        for (int sl = 0; sl < 4; ++sl) {
            int r = tid * 4 + sl;
            s += dist_l[r] + fsq_l[r];
        }
        out[(size_t)rb * 16 + tid] = 0.3125f * s;  // 1.25 / 4
    }

    // ---- gather out rows: 4 threads per row ----
    {
        const int row = tid >> 2;     // 0..63
        const int q   = tid & 3;
        const int j   = j_l[row];
        const float4* src = (const float4*)(W + (size_t)j * DIM + q * 32);
        float4* dst = (float4*)(out + 8192 + ((size_t)(rb * BM + row)) * DIM + q * 32);
        #pragma unroll
        for (int k8 = 0; k8 < 8; ++k8) dst[k8] = src[k8];
    }
}

extern "C" void kernel_launch(void* const* d_in, const int* in_sizes, int n_in,
                              void* d_out, int out_size, void* d_ws, size_t ws_size,
                              hipStream_t stream) {
    const float* feature = (const float*)d_in[0];
    const float* W       = (const float*)d_in[1];
    float*       out     = (float*)d_out;
    (void)d_ws; (void)ws_size;

    vq_fused<<<512, 256, 0, stream>>>(feature, W, out);
}